// Round 6
// baseline (416.541 us; speedup 1.0000x reference)
//
#include <hip/hip_runtime.h>

#define D 128
#define SCAN_B 1024
#define WPADH 132   // LDS W row stride in halfs (264 B): 2-way banks (free), 8B-aligned

static inline int ceil_div_ll(long long a, int b) { return (int)((a + b - 1) / b); }

typedef unsigned int uint32;
typedef unsigned short ushort16;

__device__ __forceinline__ float blo(uint32 u) { return __uint_as_float(u << 16); }
__device__ __forceinline__ float bhi(uint32 u) { return __uint_as_float(u & 0xffff0000u); }
__device__ __forceinline__ uint32 bpack(float a, float b) {   // 2x f32 -> bf16x2 RTNE
    uint32 ua = __float_as_uint(a);
    uint32 ub = __float_as_uint(b);
    ua += 0x7fffu + ((ua >> 16) & 1u);
    ub += 0x7fffu + ((ub >> 16) & 1u);
    return (ua >> 16) | (ub & 0xffff0000u);
}

// deg[i] = 1.0 (self loop), cnt[i] = 0
__global__ void k_init(float* __restrict__ deg, int* __restrict__ cnt, int n) {
    int i = blockIdx.x * blockDim.x + threadIdx.x;
    if (i < n) { deg[i] = 1.0f; cnt[i] = 0; }
}

// deg[col[e]] += 1 (normalization);  cnt[row[e]] += 1 (CSR histogram)
__global__ void k_count(const int* __restrict__ ei, float* __restrict__ deg,
                        int* __restrict__ cnt, int E) {
    int e = blockIdx.x * blockDim.x + threadIdx.x;
    if (e < E) {
        int r = ei[e];
        int c = ei[(long long)E + e];
        unsafeAtomicAdd(&deg[c], 1.0f);
        atomicAdd(&cnt[r], 1);
    }
}

// ---- two-level exclusive scan of cnt -> rp ----
__global__ __launch_bounds__(SCAN_B) void k_scan1(const int* __restrict__ cnt,
                                                  int* __restrict__ rp,
                                                  int* __restrict__ bsum, int n) {
    __shared__ int sh[SCAN_B];
    const int tid = threadIdx.x;
    const int i = blockIdx.x * SCAN_B + tid;
    int v = (i < n) ? cnt[i] : 0;
    sh[tid] = v;
    __syncthreads();
    for (int off = 1; off < SCAN_B; off <<= 1) {
        int t = (tid >= off) ? sh[tid - off] : 0;
        __syncthreads();
        sh[tid] += t;
        __syncthreads();
    }
    if (i < n) rp[i] = sh[tid] - v;
    if (tid == SCAN_B - 1) bsum[blockIdx.x] = sh[SCAN_B - 1];
}

__global__ __launch_bounds__(SCAN_B) void k_scan2(int* __restrict__ bsum,
                                                  int* __restrict__ rp, int nb, int n) {
    __shared__ int sh[SCAN_B];
    const int tid = threadIdx.x;
    int v = (tid < nb) ? bsum[tid] : 0;
    sh[tid] = v;
    __syncthreads();
    for (int off = 1; off < SCAN_B; off <<= 1) {
        int t = (tid >= off) ? sh[tid - off] : 0;
        __syncthreads();
        sh[tid] += t;
        __syncthreads();
    }
    if (tid < nb) bsum[tid] = sh[tid] - v;
    if (tid == SCAN_B - 1) rp[n] = sh[SCAN_B - 1];
}

// final scan pass + deg -> deg^(-1/2) fused
__global__ void k_scan3(int* __restrict__ rp, int* __restrict__ cur,
                        const int* __restrict__ bsum, float* __restrict__ dinv, int n) {
    int i = blockIdx.x * blockDim.x + threadIdx.x;
    if (i < n) {
        int v = rp[i] + bsum[i >> 10];
        rp[i] = v;
        cur[i] = v;
        dinv[i] = rsqrtf(dinv[i]);
    }
}

// scatter edges into CSR slots as packed {col, weight_bits}
__global__ void k_fill(const int* __restrict__ ei, const float* __restrict__ dinv,
                       int* __restrict__ cur, int2* __restrict__ e8, int E) {
    int e = blockIdx.x * blockDim.x + threadIdx.x;
    if (e < E) {
        int r = ei[e];
        int c = ei[(long long)E + e];
        float w = dinv[r] * dinv[c];
        int pos = atomicAdd(&cur[r], 1);
        int2 p; p.x = c; p.y = __float_as_int(w);
        e8[pos] = p;
    }
}

// out[r][:] = dinv[r]^2 * xin[r][:] + sum_e w_e * xin[col_e][:]
// 4 rows per wave, 16 lanes per row (16B/lane), 2-edge unroll. Output bf16x2.
template <bool IN_BF16>
__global__ __launch_bounds__(256) void k_spmm(const void* __restrict__ xin,
                                              const int* __restrict__ rp,
                                              const int2* __restrict__ e8,
                                              const float* __restrict__ dinv,
                                              uint32* __restrict__ outh, int n) {
    const int row = (blockIdx.x << 4) + (threadIdx.x >> 4);
    if (row >= n) return;
    const int sub = threadIdx.x & 15;

    float s = dinv[row];
    s *= s;
    float a0, a1, a2, a3, a4, a5, a6, a7;
    if (IN_BF16) {
        const uint4 sv = ((const uint4*)xin)[((long long)row << 4) + sub];
        a0 = s * blo(sv.x); a1 = s * bhi(sv.x); a2 = s * blo(sv.y); a3 = s * bhi(sv.y);
        a4 = s * blo(sv.z); a5 = s * bhi(sv.z); a6 = s * blo(sv.w); a7 = s * bhi(sv.w);
    } else {
        const float4 s0 = ((const float4*)xin)[((long long)row << 5) + (sub << 1)];
        const float4 s1 = ((const float4*)xin)[((long long)row << 5) + (sub << 1) + 1];
        a0 = s * s0.x; a1 = s * s0.y; a2 = s * s0.z; a3 = s * s0.w;
        a4 = s * s1.x; a5 = s * s1.y; a6 = s * s1.z; a7 = s * s1.w;
    }

    int e = rp[row];
    const int end = rp[row + 1];
    for (; e + 1 < end; e += 2) {
        const int2 p0 = e8[e], p1 = e8[e + 1];
        const float w0 = __int_as_float(p0.y), w1 = __int_as_float(p1.y);
        if (IN_BF16) {
            const uint4 v0 = ((const uint4*)xin)[((long long)p0.x << 4) + sub];
            const uint4 v1 = ((const uint4*)xin)[((long long)p1.x << 4) + sub];
            a0 += w0 * blo(v0.x) + w1 * blo(v1.x);
            a1 += w0 * bhi(v0.x) + w1 * bhi(v1.x);
            a2 += w0 * blo(v0.y) + w1 * blo(v1.y);
            a3 += w0 * bhi(v0.y) + w1 * bhi(v1.y);
            a4 += w0 * blo(v0.z) + w1 * blo(v1.z);
            a5 += w0 * bhi(v0.z) + w1 * bhi(v1.z);
            a6 += w0 * blo(v0.w) + w1 * blo(v1.w);
            a7 += w0 * bhi(v0.w) + w1 * bhi(v1.w);
        } else {
            const float4 u0 = ((const float4*)xin)[((long long)p0.x << 5) + (sub << 1)];
            const float4 u1 = ((const float4*)xin)[((long long)p0.x << 5) + (sub << 1) + 1];
            const float4 t0 = ((const float4*)xin)[((long long)p1.x << 5) + (sub << 1)];
            const float4 t1 = ((const float4*)xin)[((long long)p1.x << 5) + (sub << 1) + 1];
            a0 += w0 * u0.x + w1 * t0.x;
            a1 += w0 * u0.y + w1 * t0.y;
            a2 += w0 * u0.z + w1 * t0.z;
            a3 += w0 * u0.w + w1 * t0.w;
            a4 += w0 * u1.x + w1 * t1.x;
            a5 += w0 * u1.y + w1 * t1.y;
            a6 += w0 * u1.z + w1 * t1.z;
            a7 += w0 * u1.w + w1 * t1.w;
        }
    }
    if (e < end) {
        const int2 p = e8[e];
        const float w = __int_as_float(p.y);
        if (IN_BF16) {
            const uint4 v = ((const uint4*)xin)[((long long)p.x << 4) + sub];
            a0 += w * blo(v.x); a1 += w * bhi(v.x); a2 += w * blo(v.y); a3 += w * bhi(v.y);
            a4 += w * blo(v.z); a5 += w * bhi(v.z); a6 += w * blo(v.w); a7 += w * bhi(v.w);
        } else {
            const float4 u0 = ((const float4*)xin)[((long long)p.x << 5) + (sub << 1)];
            const float4 u1 = ((const float4*)xin)[((long long)p.x << 5) + (sub << 1) + 1];
            a0 += w * u0.x; a1 += w * u0.y; a2 += w * u0.z; a3 += w * u0.w;
            a4 += w * u1.x; a5 += w * u1.y; a6 += w * u1.z; a7 += w * u1.w;
        }
    }

    uint4 o;
    o.x = bpack(a0, a1); o.y = bpack(a2, a3); o.z = bpack(a4, a5); o.w = bpack(a6, a7);
    ((uint4*)outh)[((long long)row << 4) + sub] = o;
}

// xout[r][:] = bf16(ah[r][:]) @ bf16(W)^T + b.  128 rows x 128 cols per block,
// 256 threads, 8x8 per thread. W staged bf16 in LDS (conflict-free 2-way).
// Out-of-place; window clamp duplicates write identical values (benign).
__global__ __launch_bounds__(256, 4) void k_gemm(const uint32* __restrict__ ah,
                                                 const float* __restrict__ Wm,
                                                 const float* __restrict__ bias,
                                                 float* __restrict__ xout, int n) {
    __shared__ ushort16 shw[128 * WPADH];   // ~33.8 KB
    __shared__ float shb[128];

    const int tid = threadIdx.x;
    const long long rowbase = (long long)blockIdx.x * 128;

    // stage W bf16: shw[j][k], j = output col
    for (int idx = tid; idx < 128 * 32; idx += 256) {
        const int j = idx >> 5;
        const int k4 = idx & 31;
        const float4 v = *(const float4*)(Wm + ((long long)j << 7) + (k4 << 2));
        uint2 pw;
        pw.x = bpack(v.x, v.y);
        pw.y = bpack(v.z, v.w);
        *(uint2*)(shw + j * WPADH + (k4 << 2)) = pw;
    }
    if (tid < 128) shb[tid] = bias[tid];
    __syncthreads();

    const int tx = tid & 15;   // cols 2tx + 32m + d
    const int ty = tid >> 4;   // 8 rows each

    long long rs = rowbase + (long long)ty * 8;
    if (rs + 8 > n) rs = (long long)n - 8;
    const uint32* abase = ah + (rs << 6);   // 64 uints (128 bf16) per row

    float acc[8][8];
#pragma unroll
    for (int i = 0; i < 8; ++i)
#pragma unroll
        for (int m = 0; m < 8; ++m) acc[i][m] = 0.0f;

    for (int k4 = 0; k4 < 32; ++k4) {
        float ar[8][4];
#pragma unroll
        for (int i = 0; i < 8; ++i) {
            const uint2 u = *(const uint2*)(abase + (i << 6) + (k4 << 1));
            ar[i][0] = blo(u.x); ar[i][1] = bhi(u.x);
            ar[i][2] = blo(u.y); ar[i][3] = bhi(u.y);
        }
#pragma unroll
        for (int m = 0; m < 4; ++m) {
#pragma unroll
            for (int d = 0; d < 2; ++d) {
                const int j = 2 * tx + 32 * m + d;
                const uint2 w2 = *(const uint2*)(shw + j * WPADH + (k4 << 2));
                const float f0 = blo(w2.x), f1 = bhi(w2.x);
                const float f2 = blo(w2.y), f3 = bhi(w2.y);
#pragma unroll
                for (int i = 0; i < 8; ++i)
                    acc[i][m * 2 + d] += ar[i][0] * f0 + ar[i][1] * f1 +
                                         ar[i][2] * f2 + ar[i][3] * f3;
            }
        }
    }

#pragma unroll
    for (int i = 0; i < 8; ++i) {
        float* orow = xout + ((rs + i) << 7);
#pragma unroll
        for (int m = 0; m < 4; ++m) {
            const int c = 2 * tx + 32 * m;
            float2 o;
            o.x = acc[i][m * 2 + 0] + shb[c + 0];
            o.y = acc[i][m * 2 + 1] + shb[c + 1];
            *(float2*)(orow + c) = o;
        }
    }
}

extern "C" void kernel_launch(void* const* d_in, const int* in_sizes, int n_in,
                              void* d_out, int out_size, void* d_ws, size_t ws_size,
                              hipStream_t stream) {
    const float* x = (const float*)d_in[0];
    const int* ei = (const int*)d_in[1];
    const float* Wm = (const float*)d_in[2];
    const float* bias = (const float*)d_in[3];
    float* out = (float*)d_out;

    const int n = in_sizes[0] / D;
    const int E = in_sizes[1] / 2;
    const int NB = (n + SCAN_B - 1) / SCAN_B;

    char* ws = (char*)d_ws;
    size_t off = 0;
    auto alloc = [&](long long bytes) {
        void* p = ws + off;
        off += (size_t)((bytes + 511) & ~511LL);
        return p;
    };
    float* dinv  = (float*)alloc((long long)n * 4);
    int* cnt     = (int*)alloc((long long)n * 4);
    int* rp      = (int*)alloc((long long)(n + 1) * 4);
    int* cur     = (int*)alloc((long long)n * 4);
    int* bsum    = (int*)alloc((long long)SCAN_B * 4);
    int2* e8     = (int2*)alloc((long long)E * 8);
    uint32* x1h  = (uint32*)alloc((long long)n * 64 * 4);   // hop1 out, bf16
    uint32* x2h  = (uint32*)alloc((long long)n * 64 * 4);   // hop2 out, bf16

    const int B = 256;

    k_init<<<ceil_div_ll(n, B), B, 0, stream>>>(dinv, cnt, n);
    k_count<<<ceil_div_ll(E, B), B, 0, stream>>>(ei, dinv, cnt, E);

    k_scan1<<<NB, SCAN_B, 0, stream>>>(cnt, rp, bsum, n);
    k_scan2<<<1, SCAN_B, 0, stream>>>(bsum, rp, NB, n);
    k_scan3<<<ceil_div_ll(n, B), B, 0, stream>>>(rp, cur, bsum, dinv, n);
    k_fill<<<ceil_div_ll(E, B), B, 0, stream>>>(ei, dinv, cur, e8, E);

    // hop 1: f32 gathers from x, bf16 out
    k_spmm<false><<<ceil_div_ll(n, 16), B, 0, stream>>>(
        (const void*)x, rp, e8, dinv, x1h, n);
    // hop 2: bf16 gathers, bf16 out
    k_spmm<true><<<ceil_div_ll(n, 16), B, 0, stream>>>(
        (const void*)x1h, rp, e8, dinv, x2h, n);

    // out = x2 @ W^T + b
    k_gemm<<<ceil_div_ll(n, 128), B, 0, stream>>>(x2h, Wm, bias, out, n);
}

// Round 8
// 217.452 us; speedup vs baseline: 1.9156x; 1.9156x over previous
//
#include <hip/hip_runtime.h>

#define D 128
#define SCAN_B 1024

static inline int ceil_div_ll(long long a, int b) { return (int)((a + b - 1) / b); }

typedef unsigned int uint32;
typedef __attribute__((ext_vector_type(8))) short short8;   // 8 x bf16 (4 VGPRs)
typedef __attribute__((ext_vector_type(4))) float f32x4;    // MFMA C/D

__device__ __forceinline__ float blo(uint32 u) { return __uint_as_float(u << 16); }
__device__ __forceinline__ float bhi(uint32 u) { return __uint_as_float(u & 0xffff0000u); }
__device__ __forceinline__ uint32 bpack(float a, float b) {   // 2x f32 -> bf16x2 RTNE
    uint32 ua = __float_as_uint(a), ub = __float_as_uint(b);
    ua += 0x7fffu + ((ua >> 16) & 1u);
    ub += 0x7fffu + ((ub >> 16) & 1u);
    return (ua >> 16) | (ub & 0xffff0000u);
}

// zero both histograms
__global__ void k_init(int* __restrict__ cntc, int* __restrict__ cntr, int n) {
    int i = blockIdx.x * blockDim.x + threadIdx.x;
    if (i < n) { cntc[i] = 0; cntr[i] = 0; }
}

// col-degree (normalization) and row-degree (CSR) histograms
__global__ void k_count(const int* __restrict__ ei, int* __restrict__ cntc,
                        int* __restrict__ cntr, int E) {
    int e = blockIdx.x * blockDim.x + threadIdx.x;
    if (e < E) {
        int r = ei[e];
        int c = ei[(long long)E + e];
        atomicAdd(&cntc[c], 1);
        atomicAdd(&cntr[r], 1);
    }
}

// ---- two-level exclusive scan of cntr -> rp ----
__global__ __launch_bounds__(SCAN_B) void k_scan1(const int* __restrict__ cnt,
                                                  int* __restrict__ rp,
                                                  int* __restrict__ bsum, int n) {
    __shared__ int sh[SCAN_B];
    const int tid = threadIdx.x;
    const int i = blockIdx.x * SCAN_B + tid;
    int v = (i < n) ? cnt[i] : 0;
    sh[tid] = v;
    __syncthreads();
    for (int off = 1; off < SCAN_B; off <<= 1) {
        int t = (tid >= off) ? sh[tid - off] : 0;
        __syncthreads();
        sh[tid] += t;
        __syncthreads();
    }
    if (i < n) rp[i] = sh[tid] - v;
    if (tid == SCAN_B - 1) bsum[blockIdx.x] = sh[SCAN_B - 1];
}

__global__ __launch_bounds__(SCAN_B) void k_scan2(int* __restrict__ bsum,
                                                  int* __restrict__ rp, int nb, int n) {
    __shared__ int sh[SCAN_B];
    const int tid = threadIdx.x;
    int v = (tid < nb) ? bsum[tid] : 0;
    sh[tid] = v;
    __syncthreads();
    for (int off = 1; off < SCAN_B; off <<= 1) {
        int t = (tid >= off) ? sh[tid - off] : 0;
        __syncthreads();
        sh[tid] += t;
        __syncthreads();
    }
    if (tid < nb) bsum[tid] = sh[tid] - v;
    if (tid == SCAN_B - 1) rp[n] = sh[SCAN_B - 1];
}

// final scan pass; cn aliases: read cntc[i], write dinv[i] (same cell)
__global__ void k_scan3(int* __restrict__ rp, int* __restrict__ cur,
                        const int* __restrict__ bsum, int* __restrict__ cn, int n) {
    int i = blockIdx.x * blockDim.x + threadIdx.x;
    if (i < n) {
        int v = rp[i] + bsum[i >> 10];
        rp[i] = v;
        cur[i] = v;
        const int c = cn[i];
        ((float*)cn)[i] = rsqrtf((float)(c + 1));
    }
}

// scatter edges into CSR slots as packed {col, weight_bits}
__global__ void k_fill(const int* __restrict__ ei, const float* __restrict__ dinv,
                       int* __restrict__ cur, int2* __restrict__ e8, int E) {
    int e = blockIdx.x * blockDim.x + threadIdx.x;
    if (e < E) {
        int r = ei[e];
        int c = ei[(long long)E + e];
        float w = dinv[r] * dinv[c];
        int pos = atomicAdd(&cur[r], 1);
        int2 p; p.x = c; p.y = __float_as_int(w);
        e8[pos] = p;
    }
}

// x (f32) -> xh (bf16 RTNE): one uint4 (8 bf16) per thread
__global__ void k_cvt(const float4* __restrict__ x, uint4* __restrict__ xh, long long total) {
    long long i = (long long)blockIdx.x * blockDim.x + threadIdx.x;
    if (i < total) {
        const float4 a = x[i * 2];
        const float4 b = x[i * 2 + 1];
        uint4 o;
        o.x = bpack(a.x, a.y); o.y = bpack(a.z, a.w);
        o.z = bpack(b.x, b.y); o.w = bpack(b.z, b.w);
        xh[i] = o;
    }
}

// out[r][:] = dinv[r]^2 * xin[r][:] + sum_e w_e * xin[col_e][:]
// ONE ROW PER WAVE: 4 edge-groups (l>>4) x 16 lanes (16B d-slice each).
// __shfl_xor(16/32) merges groups; group 0 adds self-term and stores bf16.
__global__ __launch_bounds__(256) void k_spmm(const uint4* __restrict__ xh,
                                              const int* __restrict__ rp,
                                              const int2* __restrict__ e8,
                                              const float* __restrict__ dinv,
                                              uint4* __restrict__ outh, int n) {
    const int row = blockIdx.x * 4 + (threadIdx.x >> 6);
    if (row >= n) return;
    const int l = threadIdx.x & 63;
    const int g = l >> 4;
    const int s = l & 15;

    float a0 = 0, a1 = 0, a2 = 0, a3 = 0, a4 = 0, a5 = 0, a6 = 0, a7 = 0;

    const int end = rp[row + 1];
    for (int e = rp[row] + g; e < end; e += 4) {
        const int2 p = e8[e];
        const float w = __int_as_float(p.y);
        const uint4 v = xh[(long long)p.x * 16 + s];
        a0 += w * blo(v.x); a1 += w * bhi(v.x);
        a2 += w * blo(v.y); a3 += w * bhi(v.y);
        a4 += w * blo(v.z); a5 += w * bhi(v.z);
        a6 += w * blo(v.w); a7 += w * bhi(v.w);
    }

    a0 += __shfl_xor(a0, 16); a1 += __shfl_xor(a1, 16);
    a2 += __shfl_xor(a2, 16); a3 += __shfl_xor(a3, 16);
    a4 += __shfl_xor(a4, 16); a5 += __shfl_xor(a5, 16);
    a6 += __shfl_xor(a6, 16); a7 += __shfl_xor(a7, 16);
    a0 += __shfl_xor(a0, 32); a1 += __shfl_xor(a1, 32);
    a2 += __shfl_xor(a2, 32); a3 += __shfl_xor(a3, 32);
    a4 += __shfl_xor(a4, 32); a5 += __shfl_xor(a5, 32);
    a6 += __shfl_xor(a6, 32); a7 += __shfl_xor(a7, 32);

    if (g == 0) {
        float sc = dinv[row];
        sc *= sc;
        const uint4 sv = xh[(long long)row * 16 + s];
        a0 += sc * blo(sv.x); a1 += sc * bhi(sv.x);
        a2 += sc * blo(sv.y); a3 += sc * bhi(sv.y);
        a4 += sc * blo(sv.z); a5 += sc * bhi(sv.z);
        a6 += sc * blo(sv.w); a7 += sc * bhi(sv.w);
        uint4 o;
        o.x = bpack(a0, a1); o.y = bpack(a2, a3);
        o.z = bpack(a4, a5); o.w = bpack(a6, a7);
        outh[(long long)row * 16 + s] = o;
    }
}

// repack bf16(W) rows into MFMA B-fragment order:
// lane l of entry (kq*8+jt) holds W[jt*16 + (l&15)][kq*32 + (l>>4)*8 .. +7]
__global__ void k_wprep(const float* __restrict__ Wm, uint4* __restrict__ wfrag) {
    const int t = blockIdx.x * 256 + threadIdx.x;   // 0..2047
    const int l = t & 63;
    const int pair = t >> 6;                        // kq*8 + jt
    const int kq = pair >> 3;
    const int jt = pair & 7;
    const int s = l & 15;
    const int g = l >> 4;
    const float* src = Wm + ((long long)(jt * 16 + s) << 7) + kq * 32 + g * 8;
    const float4 w0 = *(const float4*)(src);
    const float4 w1 = *(const float4*)(src + 4);
    uint4 o;
    o.x = bpack(w0.x, w0.y); o.y = bpack(w0.z, w0.w);
    o.z = bpack(w1.x, w1.y); o.w = bpack(w1.z, w1.w);
    wfrag[pair * 64 + l] = o;
}

// C[r][:] = bf16(A[r][:]) @ bf16(W)^T + b via mfma_f32_16x16x32_bf16.
// Block = 4 waves x 64 rows = 256 rows, all 128 cols. NO LDS.
// Wave row-window clamped to [n-64, n) at the tail: overlapping waves
// recompute identical rows (benign duplicate stores), so no reads past n.
__global__ __launch_bounds__(256, 2) void k_gemm(const short8* __restrict__ A8,
                                                 const short8* __restrict__ wfrag,
                                                 const float* __restrict__ bias,
                                                 float* __restrict__ xout, int n) {
    const int wid = threadIdx.x >> 6;
    const int l = threadIdx.x & 63;
    const int ls = l & 15;
    const int lg = l >> 4;
    long long row0 = (long long)blockIdx.x * 256 + wid * 64;
    if (row0 + 64 > n) row0 = (long long)n - 64;

    float breg[8];
#pragma unroll
    for (int jt = 0; jt < 8; ++jt) breg[jt] = bias[jt * 16 + ls];

    f32x4 acc[4][8] = {};

#pragma unroll
    for (int kq = 0; kq < 4; ++kq) {
        short8 af[4];
#pragma unroll
        for (int m = 0; m < 4; ++m)
            af[m] = A8[(row0 + m * 16 + ls) * 16 + kq * 4 + lg];
#pragma unroll
        for (int jt = 0; jt < 8; ++jt) {
            const short8 bf = wfrag[(kq * 8 + jt) * 64 + l];
#pragma unroll
            for (int m = 0; m < 4; ++m)
                acc[m][jt] = __builtin_amdgcn_mfma_f32_16x16x32_bf16(
                    af[m], bf, acc[m][jt], 0, 0, 0);
        }
    }

#pragma unroll
    for (int m = 0; m < 4; ++m) {
#pragma unroll
        for (int q = 0; q < 4; ++q) {
            const long long row = row0 + m * 16 + lg * 4 + q;
            float* orow = xout + (row << 7);
#pragma unroll
            for (int jt = 0; jt < 8; ++jt)
                orow[jt * 16 + ls] = acc[m][jt][q] + breg[jt];
        }
    }
}

extern "C" void kernel_launch(void* const* d_in, const int* in_sizes, int n_in,
                              void* d_out, int out_size, void* d_ws, size_t ws_size,
                              hipStream_t stream) {
    const float* x = (const float*)d_in[0];
    const int* ei = (const int*)d_in[1];
    const float* Wm = (const float*)d_in[2];
    const float* bias = (const float*)d_in[3];
    float* out = (float*)d_out;

    const int n = in_sizes[0] / D;
    const int E = in_sizes[1] / 2;
    const int NB = (n + SCAN_B - 1) / SCAN_B;

    char* ws = (char*)d_ws;
    size_t off = 0;
    auto alloc = [&](long long bytes) {
        void* p = ws + off;
        off += (size_t)((bytes + 511) & ~511LL);
        return p;
    };
    int* cntc   = (int*)alloc((long long)n * 4);       // reused as dinv after scan3
    int* cntr   = (int*)alloc((long long)n * 4);       // reused as cur after scan1
    int* rp     = (int*)alloc((long long)(n + 1) * 4);
    int* bsum   = (int*)alloc((long long)SCAN_B * 4);
    int2* e8    = (int2*)alloc((long long)E * 8);
    uint4* xh   = (uint4*)alloc((long long)n * 256);   // bf16 x -> hop2 output (row=256B!)
    uint4* x1h  = (uint4*)alloc((long long)n * 256);   // bf16 hop1 output
    uint4* wfrag= (uint4*)alloc(2048LL * 16);          // 32 KB B-fragments
    float* dinv = (float*)cntc;
    int* cur    = cntr;

    const int B = 256;

    k_init<<<ceil_div_ll(n, B), B, 0, stream>>>(cntc, cntr, n);
    k_count<<<ceil_div_ll(E, B), B, 0, stream>>>(ei, cntc, cntr, E);

    k_scan1<<<NB, SCAN_B, 0, stream>>>(cntr, rp, bsum, n);
    k_scan2<<<1, SCAN_B, 0, stream>>>(bsum, rp, NB, n);
    k_scan3<<<ceil_div_ll(n, B), B, 0, stream>>>(rp, cur, bsum, cntc, n);
    k_fill<<<ceil_div_ll(E, B), B, 0, stream>>>(ei, dinv, cur, e8, E);

    // x -> bf16
    const long long tot = (long long)n * 16;     // uint4s
    k_cvt<<<ceil_div_ll(tot, B), B, 0, stream>>>((const float4*)x, xh, tot);

    // hop 1: x1h = A_norm @ xh ; hop 2: xh = A_norm @ x1h  (xh dead after hop 1)
    k_spmm<<<ceil_div_ll(n, 4), B, 0, stream>>>(xh, rp, e8, dinv, x1h, n);
    k_spmm<<<ceil_div_ll(n, 4), B, 0, stream>>>(x1h, rp, e8, dinv, xh, n);

    // W fragment repack + MFMA GEMM
    k_wprep<<<8, B, 0, stream>>>(Wm, wfrag);
    k_gemm<<<ceil_div_ll(n, 256), B, 0, stream>>>(
        (const short8*)xh, (const short8*)wfrag, bias, out, n);
}

// Round 9
// 213.397 us; speedup vs baseline: 1.9519x; 1.0190x over previous
//
#include <hip/hip_runtime.h>

#define D 128
#define SCAN_B 1024

static inline int ceil_div_ll(long long a, int b) { return (int)((a + b - 1) / b); }

typedef unsigned int uint32;
typedef __attribute__((ext_vector_type(8))) short short8;   // 8 x bf16 (4 VGPRs)
typedef __attribute__((ext_vector_type(4))) float f32x4;    // MFMA C/D

__device__ __forceinline__ float blo(uint32 u) { return __uint_as_float(u << 16); }
__device__ __forceinline__ float bhi(uint32 u) { return __uint_as_float(u & 0xffff0000u); }
__device__ __forceinline__ uint32 bpack(float a, float b) {   // 2x f32 -> bf16x2 RTNE
    uint32 ua = __float_as_uint(a), ub = __float_as_uint(b);
    ua += 0x7fffu + ((ua >> 16) & 1u);
    ub += 0x7fffu + ((ub >> 16) & 1u);
    return (ua >> 16) | (ub & 0xffff0000u);
}

// zero packed histogram
__global__ void k_init(uint32* __restrict__ cnt, int n) {
    int i = blockIdx.x * blockDim.x + threadIdx.x;
    if (i < n) cnt[i] = 0;
}

// packed histogram: cnt[c] += 1 (col-degree, low 16), cnt[r] += 1<<16 (row-degree)
// 2 edges per thread via int2 loads.
__global__ void k_count(const int2* __restrict__ rows2, const int2* __restrict__ cols2,
                        uint32* __restrict__ cnt, int E2, int odd,
                        const int* __restrict__ rows, const int* __restrict__ cols) {
    int t = blockIdx.x * blockDim.x + threadIdx.x;
    if (t < E2) {
        const int2 r2 = rows2[t];
        const int2 c2 = cols2[t];
        atomicAdd(&cnt[r2.x], 0x10000u);
        atomicAdd(&cnt[c2.x], 1u);
        atomicAdd(&cnt[r2.y], 0x10000u);
        atomicAdd(&cnt[c2.y], 1u);
    } else if (t == E2 && odd) {
        atomicAdd(&cnt[rows[2 * E2]], 0x10000u);
        atomicAdd(&cnt[cols[2 * E2]], 1u);
    }
}

// ---- two-level exclusive scan of row-degrees (cnt >> 16) -> rp ----
__global__ __launch_bounds__(SCAN_B) void k_scan1(const uint32* __restrict__ cnt,
                                                  int* __restrict__ rp,
                                                  int* __restrict__ bsum, int n) {
    __shared__ int sh[SCAN_B];
    const int tid = threadIdx.x;
    const int i = blockIdx.x * SCAN_B + tid;
    int v = (i < n) ? (int)(cnt[i] >> 16) : 0;
    sh[tid] = v;
    __syncthreads();
    for (int off = 1; off < SCAN_B; off <<= 1) {
        int t = (tid >= off) ? sh[tid - off] : 0;
        __syncthreads();
        sh[tid] += t;
        __syncthreads();
    }
    if (i < n) rp[i] = sh[tid] - v;
    if (tid == SCAN_B - 1) bsum[blockIdx.x] = sh[SCAN_B - 1];
}

__global__ __launch_bounds__(SCAN_B) void k_scan2(int* __restrict__ bsum,
                                                  int* __restrict__ rp, int nb, int n) {
    __shared__ int sh[SCAN_B];
    const int tid = threadIdx.x;
    int v = (tid < nb) ? bsum[tid] : 0;
    sh[tid] = v;
    __syncthreads();
    for (int off = 1; off < SCAN_B; off <<= 1) {
        int t = (tid >= off) ? sh[tid - off] : 0;
        __syncthreads();
        sh[tid] += t;
        __syncthreads();
    }
    if (tid < nb) bsum[tid] = sh[tid] - v;
    if (tid == SCAN_B - 1) rp[n] = sh[SCAN_B - 1];
}

// final scan pass; unpack col-degree from cnt low half, overwrite cnt as dinv (f32)
__global__ void k_scan3(int* __restrict__ rp, int* __restrict__ cur,
                        const int* __restrict__ bsum, uint32* __restrict__ cnt, int n) {
    int i = blockIdx.x * blockDim.x + threadIdx.x;
    if (i < n) {
        int v = rp[i] + bsum[i >> 10];
        rp[i] = v;
        cur[i] = v;
        const uint32 c = cnt[i] & 0xffffu;
        ((float*)cnt)[i] = rsqrtf((float)(c + 1));
    }
}

// scatter edges into CSR slots as packed {col, weight_bits}; 2 edges per thread
__global__ void k_fill(const int2* __restrict__ rows2, const int2* __restrict__ cols2,
                       const float* __restrict__ dinv, int* __restrict__ cur,
                       int2* __restrict__ e8, int E2, int odd,
                       const int* __restrict__ rows, const int* __restrict__ cols) {
    int t = blockIdx.x * blockDim.x + threadIdx.x;
    if (t < E2) {
        const int2 r2 = rows2[t];
        const int2 c2 = cols2[t];
        const float w0 = dinv[r2.x] * dinv[c2.x];
        const float w1 = dinv[r2.y] * dinv[c2.y];
        const int p0 = atomicAdd(&cur[r2.x], 1);
        int2 q0; q0.x = c2.x; q0.y = __float_as_int(w0);
        e8[p0] = q0;
        const int p1 = atomicAdd(&cur[r2.y], 1);
        int2 q1; q1.x = c2.y; q1.y = __float_as_int(w1);
        e8[p1] = q1;
    } else if (t == E2 && odd) {
        const int r = rows[2 * E2], c = cols[2 * E2];
        const float w = dinv[r] * dinv[c];
        const int p = atomicAdd(&cur[r], 1);
        int2 q; q.x = c; q.y = __float_as_int(w);
        e8[p] = q;
    }
}

// x (f32) -> xh (bf16 RTNE): one uint4 (8 bf16) per thread
__global__ void k_cvt(const float4* __restrict__ x, uint4* __restrict__ xh, long long total) {
    long long i = (long long)blockIdx.x * blockDim.x + threadIdx.x;
    if (i < total) {
        const float4 a = x[i * 2];
        const float4 b = x[i * 2 + 1];
        uint4 o;
        o.x = bpack(a.x, a.y); o.y = bpack(a.z, a.w);
        o.z = bpack(b.x, b.y); o.w = bpack(b.z, b.w);
        xh[i] = o;
    }
}

// out[r][:] = dinv[r]^2 * xin[r][:] + sum_e w_e * xin[col_e][:]
// ONE ROW PER WAVE: 4 edge-groups (l>>4) x 16 lanes (16B d-slice each).
// Self-term gather issued BEFORE the edge loop (latency overlapped; lines merge).
// __shfl_xor(16/32) merges groups; group 0 stores bf16.
__global__ __launch_bounds__(256) void k_spmm(const uint4* __restrict__ xh,
                                              const int* __restrict__ rp,
                                              const int2* __restrict__ e8,
                                              const float* __restrict__ dinv,
                                              uint4* __restrict__ outh, int n) {
    const int row = blockIdx.x * 4 + (threadIdx.x >> 6);
    if (row >= n) return;
    const int l = threadIdx.x & 63;
    const int g = l >> 4;
    const int s = l & 15;

    const float dv = dinv[row];
    const uint4 sv = xh[(long long)row * 16 + s];   // 4-way dup, lines merge in-wave
    const float sc = (g == 0) ? dv * dv : 0.0f;

    float a0 = sc * blo(sv.x), a1 = sc * bhi(sv.x);
    float a2 = sc * blo(sv.y), a3 = sc * bhi(sv.y);
    float a4 = sc * blo(sv.z), a5 = sc * bhi(sv.z);
    float a6 = sc * blo(sv.w), a7 = sc * bhi(sv.w);

    const int end = rp[row + 1];
    for (int e = rp[row] + g; e < end; e += 4) {
        const int2 p = e8[e];
        const float w = __int_as_float(p.y);
        const uint4 v = xh[(long long)p.x * 16 + s];
        a0 += w * blo(v.x); a1 += w * bhi(v.x);
        a2 += w * blo(v.y); a3 += w * bhi(v.y);
        a4 += w * blo(v.z); a5 += w * bhi(v.z);
        a6 += w * blo(v.w); a7 += w * bhi(v.w);
    }

    a0 += __shfl_xor(a0, 16); a1 += __shfl_xor(a1, 16);
    a2 += __shfl_xor(a2, 16); a3 += __shfl_xor(a3, 16);
    a4 += __shfl_xor(a4, 16); a5 += __shfl_xor(a5, 16);
    a6 += __shfl_xor(a6, 16); a7 += __shfl_xor(a7, 16);
    a0 += __shfl_xor(a0, 32); a1 += __shfl_xor(a1, 32);
    a2 += __shfl_xor(a2, 32); a3 += __shfl_xor(a3, 32);
    a4 += __shfl_xor(a4, 32); a5 += __shfl_xor(a5, 32);
    a6 += __shfl_xor(a6, 32); a7 += __shfl_xor(a7, 32);

    if (g == 0) {
        uint4 o;
        o.x = bpack(a0, a1); o.y = bpack(a2, a3);
        o.z = bpack(a4, a5); o.w = bpack(a6, a7);
        outh[(long long)row * 16 + s] = o;
    }
}

// repack bf16(W) rows into MFMA B-fragment order:
// lane l of entry (kq*8+jt) holds W[jt*16 + (l&15)][kq*32 + (l>>4)*8 .. +7]
__global__ void k_wprep(const float* __restrict__ Wm, uint4* __restrict__ wfrag) {
    const int t = blockIdx.x * 256 + threadIdx.x;   // 0..2047
    const int l = t & 63;
    const int pair = t >> 6;                        // kq*8 + jt
    const int kq = pair >> 3;
    const int jt = pair & 7;
    const int s = l & 15;
    const int g = l >> 4;
    const float* src = Wm + ((long long)(jt * 16 + s) << 7) + kq * 32 + g * 8;
    const float4 w0 = *(const float4*)(src);
    const float4 w1 = *(const float4*)(src + 4);
    uint4 o;
    o.x = bpack(w0.x, w0.y); o.y = bpack(w0.z, w0.w);
    o.z = bpack(w1.x, w1.y); o.w = bpack(w1.z, w1.w);
    wfrag[pair * 64 + l] = o;
}

// C[r][:] = bf16(A[r][:]) @ bf16(W)^T + b via mfma_f32_16x16x32_bf16.
// Block = 4 waves x 64 rows = 256 rows, all 128 cols. NO LDS.
// Tail waves clamp to [n-64, n): duplicate stores of identical values, no OOB reads.
__global__ __launch_bounds__(256, 2) void k_gemm(const short8* __restrict__ A8,
                                                 const short8* __restrict__ wfrag,
                                                 const float* __restrict__ bias,
                                                 float* __restrict__ xout, int n) {
    const int wid = threadIdx.x >> 6;
    const int l = threadIdx.x & 63;
    const int ls = l & 15;
    const int lg = l >> 4;
    long long row0 = (long long)blockIdx.x * 256 + wid * 64;
    if (row0 + 64 > n) row0 = (long long)n - 64;

    float breg[8];
#pragma unroll
    for (int jt = 0; jt < 8; ++jt) breg[jt] = bias[jt * 16 + ls];

    f32x4 acc[4][8] = {};

#pragma unroll
    for (int kq = 0; kq < 4; ++kq) {
        short8 af[4];
#pragma unroll
        for (int m = 0; m < 4; ++m)
            af[m] = A8[(row0 + m * 16 + ls) * 16 + kq * 4 + lg];
#pragma unroll
        for (int jt = 0; jt < 8; ++jt) {
            const short8 bf = wfrag[(kq * 8 + jt) * 64 + l];
#pragma unroll
            for (int m = 0; m < 4; ++m)
                acc[m][jt] = __builtin_amdgcn_mfma_f32_16x16x32_bf16(
                    af[m], bf, acc[m][jt], 0, 0, 0);
        }
    }

#pragma unroll
    for (int m = 0; m < 4; ++m) {
#pragma unroll
        for (int q = 0; q < 4; ++q) {
            const long long row = row0 + m * 16 + lg * 4 + q;
            float* orow = xout + (row << 7);
#pragma unroll
            for (int jt = 0; jt < 8; ++jt)
                orow[jt * 16 + ls] = acc[m][jt][q] + breg[jt];
        }
    }
}

extern "C" void kernel_launch(void* const* d_in, const int* in_sizes, int n_in,
                              void* d_out, int out_size, void* d_ws, size_t ws_size,
                              hipStream_t stream) {
    const float* x = (const float*)d_in[0];
    const int* ei = (const int*)d_in[1];
    const float* Wm = (const float*)d_in[2];
    const float* bias = (const float*)d_in[3];
    float* out = (float*)d_out;

    const int n = in_sizes[0] / D;
    const int E = in_sizes[1] / 2;
    const int E2 = E >> 1;
    const int odd = E & 1;
    const int NB = (n + SCAN_B - 1) / SCAN_B;

    char* ws = (char*)d_ws;
    size_t off = 0;
    auto alloc = [&](long long bytes) {
        void* p = ws + off;
        off += (size_t)((bytes + 511) & ~511LL);
        return p;
    };
    uint32* cnt = (uint32*)alloc((long long)n * 4);    // packed hist -> dinv (f32) after scan3
    int* cur    = (int*)alloc((long long)n * 4);
    int* rp     = (int*)alloc((long long)(n + 1) * 4);
    int* bsum   = (int*)alloc((long long)SCAN_B * 4);
    int2* e8    = (int2*)alloc((long long)E * 8);
    uint4* xh   = (uint4*)alloc((long long)n * 256);   // bf16 x; reused as hop-2 output
    uint4* x1h  = (uint4*)alloc((long long)n * 256);   // bf16 hop-1 output
    uint4* wfrag= (uint4*)alloc(2048LL * 16);          // 32 KB B-fragments
    float* dinv = (float*)cnt;

    const int* rows = ei;
    const int* cols = ei + E;
    const int2* rows2 = (const int2*)rows;
    const int2* cols2 = (const int2*)cols;

    const int B = 256;

    k_init<<<ceil_div_ll(n, B), B, 0, stream>>>(cnt, n);
    k_count<<<ceil_div_ll(E2 + 1, B), B, 0, stream>>>(rows2, cols2, cnt, E2, odd, rows, cols);

    k_scan1<<<NB, SCAN_B, 0, stream>>>(cnt, rp, bsum, n);
    k_scan2<<<1, SCAN_B, 0, stream>>>(bsum, rp, NB, n);
    k_scan3<<<ceil_div_ll(n, B), B, 0, stream>>>(rp, cur, bsum, cnt, n);
    k_fill<<<ceil_div_ll(E2 + 1, B), B, 0, stream>>>(rows2, cols2, dinv, cur, e8, E2, odd, rows, cols);

    // x -> bf16
    const long long tot = (long long)n * 16;     // uint4s
    k_cvt<<<ceil_div_ll(tot, B), B, 0, stream>>>((const float4*)x, xh, tot);

    // hop 1: x1h = A_norm @ xh ; hop 2: xh = A_norm @ x1h  (xh dead after hop 1)
    k_spmm<<<ceil_div_ll(n, 4), B, 0, stream>>>(xh, rp, e8, dinv, x1h, n);
    k_spmm<<<ceil_div_ll(n, 4), B, 0, stream>>>(x1h, rp, e8, dinv, xh, n);

    // W fragment repack + MFMA GEMM
    k_wprep<<<8, B, 0, stream>>>(Wm, wfrag);
    k_gemm<<<ceil_div_ll(n, 256), B, 0, stream>>>(
        (const short8*)xh, (const short8*)wfrag, bias, out, n);
}